// Round 5
// baseline (815.022 us; speedup 1.0000x reference)
//
#include <hip/hip_runtime.h>
#include <stdint.h>

typedef float  f32x4  __attribute__((ext_vector_type(4)));
typedef short  short8 __attribute__((ext_vector_type(8)));
typedef __bf16 bf16x8 __attribute__((ext_vector_type(8)));

__device__ __forceinline__ unsigned short f2bf(float f) {
    unsigned u = __builtin_bit_cast(unsigned, f);
    unsigned r = u + 0x7fffu + ((u >> 16) & 1u);   // round-to-nearest-even
    return (unsigned short)(r >> 16);
}

__device__ __forceinline__ short8 cvt8(f32x4 a, f32x4 b) {
    short8 r;
    r[0] = (short)f2bf(a[0]); r[1] = (short)f2bf(a[1]);
    r[2] = (short)f2bf(a[2]); r[3] = (short)f2bf(a[3]);
    r[4] = (short)f2bf(b[0]); r[5] = (short)f2bf(b[1]);
    r[6] = (short)f2bf(b[2]); r[7] = (short)f2bf(b[3]);
    return r;
}

typedef const __attribute__((address_space(1))) void* gas_p;
typedef __attribute__((address_space(3))) void*       las_p;
__device__ __forceinline__ void gld_lds16(const void* g, void* l) {
    __builtin_amdgcn_global_load_lds((gas_p)g, (las_p)l, 16, 0, 0);
}

__device__ __forceinline__ f32x4 mfma16(short8 a, short8 b, f32x4 c) {
    return __builtin_amdgcn_mfma_f32_16x16x32_bf16(
        __builtin_bit_cast(bf16x8, a), __builtin_bit_cast(bf16x8, b), c, 0, 0, 0);
}

// ---------------------------------------------------------------------------
// Small GEMM:  St[n][m] = sum_k X[m][k] * W[k][n]   (K = 128 fixed)
// (unchanged — validated, ~2% of runtime)
// ---------------------------------------------------------------------------
template<int NMAT>
__global__ __launch_bounds__(256) void k_xw_t(const float* __restrict__ X,
                                              const float* __restrict__ W,
                                              short* __restrict__ St, int M) {
    constexpr int K   = 128;
    constexpr int NPT = NMAT / 4;
    __shared__ float Xs[64][129];
    __shared__ float Ws[K][NMAT];

    const int tid = threadIdx.x;
    const int m0  = blockIdx.x * 64;

    constexpr int WCH = K * NMAT / 4 / 256;
    #pragma unroll
    for (int j = 0; j < WCH; ++j) {
        int ch = tid + j * 256;
        ((float4*)Ws)[ch] = ((const float4*)W)[ch];
    }
    #pragma unroll
    for (int j = 0; j < 8; ++j) {
        int ch = tid + j * 256;
        int r = ch >> 5, c4 = ch & 31;
        float4 v = *(const float4*)(X + (size_t)(m0 + r) * K + c4 * 4);
        Xs[r][c4 * 4 + 0] = v.x; Xs[r][c4 * 4 + 1] = v.y;
        Xs[r][c4 * 4 + 2] = v.z; Xs[r][c4 * 4 + 3] = v.w;
    }
    __syncthreads();

    const int m  = tid & 63;
    const int n0 = (tid >> 6) * NPT;
    float acc[NPT];
    #pragma unroll
    for (int i = 0; i < NPT; ++i) acc[i] = 0.f;

    for (int k = 0; k < K; ++k) {
        float x = Xs[m][k];
        #pragma unroll
        for (int i = 0; i < NPT; i += 4) {
            float4 w = *(const float4*)&Ws[k][n0 + i];
            acc[i + 0] += x * w.x; acc[i + 1] += x * w.y;
            acc[i + 2] += x * w.z; acc[i + 3] += x * w.w;
        }
    }
    #pragma unroll
    for (int i = 0; i < NPT; ++i)
        St[(size_t)(n0 + i) * M + m0 + m] = (short)f2bf(acc[i]);
}

// ---------------------------------------------------------------------------
// Streaming GEMM:  out[m][n] = sum_k adj[m][k] * S[k][n]  (+bias, opt. relu)
//  v5: occupancy 2 waves/SIMD.
//  - BM=16, 128 threads (2 waves), grid 1024 -> 4 blocks/CU, 8 waves/CU.
//    Twin waves SPLIT N: wave w owns cols [w*BN/2, (w+1)*BN/2); both read the
//    same 16 A-rows (duplicate loads dedup'd by L1/L2 MSHR merge).
//  - A: global->reg dwordx4, 2 tiles deep, cvt to bf16 in reg. Never in LDS.
//  - B: cooperative global_load_lds DMA, double-buffered, pre-swizzled source
//    (XOR (row&7)<<4, linear LDS dest) -> conflict-free ds_read_b128.
//  - Counted vmcnt (never 0) + raw s_barrier + sched_barrier(0): prefetched
//    loads persist across barriers. Clamped tail keeps counts uniform.
//  - Prologue A(0), B(0), A(1): B(0) followed by exactly 4 per-wave A-loads,
//    so vmcnt(BCH+8) is exact at ITER(0) (steady-state-identical).
// ---------------------------------------------------------------------------
template<int BN, bool RELU>
__global__ __launch_bounds__(128, 2) void k_adj_gemm(const float* __restrict__ A,
                                                     const short* __restrict__ Bt,
                                                     const float* __restrict__ bias,
                                                     float* __restrict__ out,
                                                     int M, int K) {
    constexpr int BM    = 16, BK = 64;
    constexpr int NF    = BN / 32;               // n-frags per wave (4 or 2)
    constexpr int BTILE = BN * BK * 2;           // B tile bytes (16384 or 8192)
    constexpr int BCH   = BTILE / (128 * 16);    // DMA instrs per thread (8 or 4)
    constexpr int VMCNT = BCH + 8;               // ops after B(t): A(t+1)x4 + B(t+1) + A(t+2)x4

    __shared__ short Bs[2][BN * 64];

    const int tid  = threadIdx.x;
    const int wave = tid >> 6, lane = tid & 63;
    const int lr   = lane & 15, lk = lane >> 4;
    const int row_g = blockIdx.x * BM + lr;      // same rows for both waves
    const int cbB   = wave * (BN / 2) * 128;     // this wave's B col-base (bytes)

    const char* Abase = (const char*)A + (size_t)row_g * K * 4 + lk * 32;

    // swizzled per-lane LDS read offsets for B frags (s=0,1)
    const int offs0 = (lk * 16)      ^ ((lr & 7) << 4);
    const int offs1 = (64 + lk * 16) ^ ((lr & 7) << 4);

    f32x4 acc[NF];
    #pragma unroll
    for (int n = 0; n < NF; ++n) acc[n] = (f32x4)0.f;

    f32x4 a0[4], a1[4];                          // A prefetch slots, 2 tiles deep
    const int NT = K / BK;                       // 256

#define STAGE_B(BUF, KT)                                                        \
    {                                                                           \
        _Pragma("unroll")                                                       \
        for (int j = 0; j < BCH; ++j) {                                         \
            int o = (tid + j * 128) * 16;        /* linear byte off in tile */  \
            int r = o >> 7, w = o & 127;                                        \
            const char* src = (const char*)Bt + (size_t)r * (K * 2)             \
                              + (size_t)(KT) * 128 + (w ^ ((r & 7) << 4));      \
            gld_lds16(src, (char*)&Bs[BUF][0] + o);                             \
        }                                                                       \
    }

#define LOAD_A(SLOT, KT)                                                        \
    {                                                                           \
        const char* p = Abase + (size_t)(KT) * 256;                             \
        SLOT[0] = *(const f32x4*)(p);                                           \
        SLOT[1] = *(const f32x4*)(p + 16);                                      \
        SLOT[2] = *(const f32x4*)(p + 128);                                     \
        SLOT[3] = *(const f32x4*)(p + 144);                                     \
    }

    // prologue (order matters for vmcnt accounting — see header comment)
    LOAD_A(a0, 0)
    STAGE_B(0, 0)
    LOAD_A(a1, 1)

#define ITER(KT, SA, CUR, NXT)                                                  \
    {                                                                           \
        /* P1: stage B(kt+1) into NXT (clamped at tail, count-uniform) */       \
        { int ktn = (KT) + 1 < NT ? (KT) + 1 : NT - 1; STAGE_B(NXT, ktn) }      \
        __builtin_amdgcn_sched_barrier(0);                                      \
        /* P2a: cvt A(kt) -> bf16 frags */                                      \
        short8 fa0 = cvt8(SA[0], SA[1]);                                        \
        short8 fa1 = cvt8(SA[2], SA[3]);                                        \
        /* P2b: refill slot with A(kt+2) */                                     \
        { int kta = (KT) + 2 < NT ? (KT) + 2 : NT - 1; LOAD_A(SA, kta) }        \
        __builtin_amdgcn_sched_barrier(0);                                      \
        /* P3: B(kt) landed; newer loads stay in flight */                      \
        asm volatile("s_waitcnt vmcnt(%0)" :: "i"(VMCNT) : "memory");           \
        __builtin_amdgcn_s_barrier();                                           \
        __builtin_amdgcn_sched_barrier(0);                                      \
        /* P4: MFMA over this wave's n-frags, both K-halves */                  \
        _Pragma("unroll")                                                       \
        for (int n = 0; n < NF; ++n) {                                          \
            short8 b0 = *(const short8*)((const char*)&Bs[CUR][0]               \
                                         + cbB + n * 2048 + lr * 128 + offs0);  \
            acc[n] = mfma16(fa0, b0, acc[n]);                                   \
            short8 b1 = *(const short8*)((const char*)&Bs[CUR][0]               \
                                         + cbB + n * 2048 + lr * 128 + offs1);  \
            acc[n] = mfma16(fa1, b1, acc[n]);                                   \
        }                                                                       \
        __builtin_amdgcn_sched_barrier(0);                                      \
        __builtin_amdgcn_s_barrier();  /* CUR free for next iter's DMA */       \
    }

    for (int g = 0; g < NT / 2; ++g) {
        ITER(2 * g,     a0, 0, 1)
        ITER(2 * g + 1, a1, 1, 0)
    }
#undef ITER
#undef LOAD_A
#undef STAGE_B

    // epilogue: D layout col = lane&15, row = (lane>>4)*4 + j  [m89-verified]
    #pragma unroll
    for (int n = 0; n < NF; ++n) {
        int col = wave * (BN / 2) + n * 16 + lr;
        float bv = bias[col];
        #pragma unroll
        for (int j = 0; j < 4; ++j) {
            int row = blockIdx.x * BM + lk * 4 + j;
            float v = acc[n][j] + bv;
            if (RELU) v = fmaxf(v, 0.f);
            out[(size_t)row * BN + col] = v;
        }
    }
}

extern "C" void kernel_launch(void* const* d_in, const int* in_sizes, int n_in,
                              void* d_out, int out_size, void* d_ws, size_t ws_size,
                              hipStream_t stream) {
    const int N = 16384, NH1 = 128, NH2 = 64;
    const float* feature = (const float*)d_in[0];
    const float* adj     = (const float*)d_in[1];
    const float* W1      = (const float*)d_in[2];
    const float* b1      = (const float*)d_in[3];
    const float* W2      = (const float*)d_in[4];
    const float* b2      = (const float*)d_in[5];

    short* S1t = (short*)d_ws;                            // [128][16384] bf16, 4 MiB
    float* h   = (float*)((char*)d_ws + (4u << 20));      // [16384][128] fp32, 8 MiB
    short* S2t = (short*)((char*)d_ws + (12u << 20));     // [64][16384]  bf16, 2 MiB

    k_xw_t<NH1><<<N / 64, 256, 0, stream>>>(feature, W1, S1t, N);
    k_adj_gemm<NH1, true ><<<N / 16, 128, 0, stream>>>(adj, S1t, b1, h, N, N);
    k_xw_t<NH2><<<N / 64, 256, 0, stream>>>(h, W2, S2t, N);
    k_adj_gemm<NH2, false><<<N / 16, 128, 0, stream>>>(adj, S2t, b2, (float*)d_out, N, N);
    (void)in_sizes; (void)n_in; (void)out_size; (void)ws_size;
}

// Round 6
// 577.905 us; speedup vs baseline: 1.4103x; 1.4103x over previous
//
#include <hip/hip_runtime.h>
#include <stdint.h>

typedef float  f32x4  __attribute__((ext_vector_type(4)));
typedef short  short8 __attribute__((ext_vector_type(8)));
typedef __bf16 bf16x8 __attribute__((ext_vector_type(8)));

__device__ __forceinline__ unsigned short f2bf(float f) {
    unsigned u = __builtin_bit_cast(unsigned, f);
    unsigned r = u + 0x7fffu + ((u >> 16) & 1u);   // round-to-nearest-even
    return (unsigned short)(r >> 16);
}

__device__ __forceinline__ short8 cvt8(f32x4 a, f32x4 b) {
    short8 r;
    r[0] = (short)f2bf(a[0]); r[1] = (short)f2bf(a[1]);
    r[2] = (short)f2bf(a[2]); r[3] = (short)f2bf(a[3]);
    r[4] = (short)f2bf(b[0]); r[5] = (short)f2bf(b[1]);
    r[6] = (short)f2bf(b[2]); r[7] = (short)f2bf(b[3]);
    return r;
}

typedef const __attribute__((address_space(1))) void* gas_p;
typedef __attribute__((address_space(3))) void*       las_p;
__device__ __forceinline__ void gld_lds16(const void* g, void* l) {
    __builtin_amdgcn_global_load_lds((gas_p)g, (las_p)l, 16, 0, 0);
}

__device__ __forceinline__ f32x4 mfma16(short8 a, short8 b, f32x4 c) {
    return __builtin_amdgcn_mfma_f32_16x16x32_bf16(
        __builtin_bit_cast(bf16x8, a), __builtin_bit_cast(bf16x8, b), c, 0, 0, 0);
}

// ---------------------------------------------------------------------------
// Small GEMM:  St[n][m] = sum_k X[m][k] * W[k][n]   (K = 128 fixed)
// (unchanged — validated, ~2% of runtime)
// ---------------------------------------------------------------------------
template<int NMAT>
__global__ __launch_bounds__(256) void k_xw_t(const float* __restrict__ X,
                                              const float* __restrict__ W,
                                              short* __restrict__ St, int M) {
    constexpr int K   = 128;
    constexpr int NPT = NMAT / 4;
    __shared__ float Xs[64][129];
    __shared__ float Ws[K][NMAT];

    const int tid = threadIdx.x;
    const int m0  = blockIdx.x * 64;

    constexpr int WCH = K * NMAT / 4 / 256;
    #pragma unroll
    for (int j = 0; j < WCH; ++j) {
        int ch = tid + j * 256;
        ((float4*)Ws)[ch] = ((const float4*)W)[ch];
    }
    #pragma unroll
    for (int j = 0; j < 8; ++j) {
        int ch = tid + j * 256;
        int r = ch >> 5, c4 = ch & 31;
        float4 v = *(const float4*)(X + (size_t)(m0 + r) * K + c4 * 4);
        Xs[r][c4 * 4 + 0] = v.x; Xs[r][c4 * 4 + 1] = v.y;
        Xs[r][c4 * 4 + 2] = v.z; Xs[r][c4 * 4 + 3] = v.w;
    }
    __syncthreads();

    const int m  = tid & 63;
    const int n0 = (tid >> 6) * NPT;
    float acc[NPT];
    #pragma unroll
    for (int i = 0; i < NPT; ++i) acc[i] = 0.f;

    for (int k = 0; k < K; ++k) {
        float x = Xs[m][k];
        #pragma unroll
        for (int i = 0; i < NPT; i += 4) {
            float4 w = *(const float4*)&Ws[k][n0 + i];
            acc[i + 0] += x * w.x; acc[i + 1] += x * w.y;
            acc[i + 2] += x * w.z; acc[i + 3] += x * w.w;
        }
    }
    #pragma unroll
    for (int i = 0; i < NPT; ++i)
        St[(size_t)(n0 + i) * M + m0 + m] = (short)f2bf(acc[i]);
}

// ---------------------------------------------------------------------------
// Streaming GEMM:  out[m][n] = sum_k adj[m][k] * S[k][n]  (+bias, opt. relu)
//  v6: 2 waves/SIMD with ZERO duplicated global reads (r5 lesson).
//  - BM=32, 256 threads / 4 waves (2M x 2N), grid 512 -> 2 blocks/CU,
//    8 waves/CU = 2 waves/SIMD.
//  - BOTH A (fp32) and B (bf16) staged via global_load_lds DMA, each byte
//    DMA'd once per block; waves read fragments from LDS (A cvt'd to bf16
//    in reg after ds_read). No A register pipeline -> no spill hazard.
//  - Both-sides XOR swizzle (row&7)<<4 on A and B (linear LDS dest,
//    pre-swizzled global source) -> conflict-free ds_read_b128.
//  - Counted vmcnt (never 0) + raw s_barrier + sched_barrier(0): prefetched
//    DMA persists across barriers. VMCNT = ACH+BCH exactly (prologue
//    steady-state-identical). Clamped tail keeps counts uniform.
// ---------------------------------------------------------------------------
template<int BN, bool RELU>
__global__ __launch_bounds__(256, 2) void k_adj_gemm(const float* __restrict__ A,
                                                     const short* __restrict__ Bt,
                                                     const float* __restrict__ bias,
                                                     float* __restrict__ out,
                                                     int M, int K) {
    constexpr int BM    = 32, BK = 64;
    constexpr int NF    = BN / 32;               // n-frags per wave (4 or 2)
    constexpr int ACH   = BM * BK * 4 / (256 * 16);   // 2 A-DMA per thread
    constexpr int BCH   = BN * BK * 2 / (256 * 16);   // 4 or 2 B-DMA per thread
    constexpr int VMCNT = ACH + BCH;             // ops after buf(t): buf(t+1) stage

    __shared__ float As[2][BM * 64];             // 8 KB per buffer
    __shared__ short Bs[2][BN * 64];             // 16/8 KB per buffer

    const int tid  = threadIdx.x;
    const int wave = tid >> 6, lane = tid & 63;
    const int lr   = lane & 15, lk = lane >> 4;
    const int wr   = wave >> 1, wc = wave & 1;
    const int row0 = blockIdx.x * BM;
    const int cbB  = wc * (BN / 2) * 128;        // this wave's B col-base (bytes)
    const int key  = (lr & 7) << 4;              // XOR swizzle key

    // per-lane LDS read offsets
    const int aRow   = (wr * 16 + lr) * 256;     // A row base (bytes)
    const int aO0    = (lk * 32) ^ key,       aO0b = (lk * 32 + 16) ^ key;
    const int aO1    = (128 + lk * 32) ^ key, aO1b = (128 + lk * 32 + 16) ^ key;
    const int offs0  = (lk * 16) ^ key;          // B k-half 0
    const int offs1  = (64 + lk * 16) ^ key;     // B k-half 1

    f32x4 acc[NF];
    #pragma unroll
    for (int n = 0; n < NF; ++n) acc[n] = (f32x4)0.f;

    const int NT = K / BK;                       // 256

#define STAGE_AB(BUF, KT)                                                       \
    {                                                                           \
        _Pragma("unroll")                                                       \
        for (int j = 0; j < ACH; ++j) {                                         \
            int o = (tid + j * 256) * 16;        /* linear byte off, A tile */  \
            int r = o >> 8, w = o & 255;                                        \
            const char* src = (const char*)A + (size_t)(row0 + r) * K * 4       \
                              + (size_t)(KT) * 256 + (w ^ ((r & 7) << 4));      \
            gld_lds16(src, (char*)&As[BUF][0] + o);                             \
        }                                                                       \
        _Pragma("unroll")                                                       \
        for (int j = 0; j < BCH; ++j) {                                         \
            int o = (tid + j * 256) * 16;        /* linear byte off, B tile */  \
            int r = o >> 7, w = o & 127;                                        \
            const char* src = (const char*)Bt + (size_t)r * (K * 2)             \
                              + (size_t)(KT) * 128 + (w ^ ((r & 7) << 4));      \
            gld_lds16(src, (char*)&Bs[BUF][0] + o);                             \
        }                                                                       \
    }

    // prologue: stage tile 0 (ACH+BCH ops -> VMCNT exact at ITER(0))
    STAGE_AB(0, 0)

#define ITER(KT, CUR, NXT)                                                      \
    {                                                                           \
        /* P1: stage tile kt+1 into NXT (clamped at tail, count-uniform) */     \
        { int ktn = (KT) + 1 < NT ? (KT) + 1 : NT - 1; STAGE_AB(NXT, ktn) }     \
        __builtin_amdgcn_sched_barrier(0);                                      \
        /* P2: buf CUR landed (my ops); newer stay in flight; then collective */\
        asm volatile("s_waitcnt vmcnt(%0)" :: "i"(VMCNT) : "memory");           \
        __builtin_amdgcn_s_barrier();                                           \
        __builtin_amdgcn_sched_barrier(0);                                      \
        /* P3: A frags from LDS, cvt fp32->bf16 */                              \
        const char* Ab = (const char*)&As[CUR][0] + aRow;                       \
        f32x4 A0a = *(const f32x4*)(Ab + aO0);                                  \
        f32x4 A0b = *(const f32x4*)(Ab + aO0b);                                 \
        f32x4 A1a = *(const f32x4*)(Ab + aO1);                                  \
        f32x4 A1b = *(const f32x4*)(Ab + aO1b);                                 \
        short8 fa0 = cvt8(A0a, A0b);                                            \
        short8 fa1 = cvt8(A1a, A1b);                                            \
        /* P4: MFMA over this wave's n-frags, both K-halves */                  \
        _Pragma("unroll")                                                       \
        for (int n = 0; n < NF; ++n) {                                          \
            short8 b0 = *(const short8*)((const char*)&Bs[CUR][0]               \
                                         + cbB + n * 2048 + lr * 128 + offs0);  \
            acc[n] = mfma16(fa0, b0, acc[n]);                                   \
            short8 b1 = *(const short8*)((const char*)&Bs[CUR][0]               \
                                         + cbB + n * 2048 + lr * 128 + offs1);  \
            acc[n] = mfma16(fa1, b1, acc[n]);                                   \
        }                                                                       \
        __builtin_amdgcn_sched_barrier(0);                                      \
        __builtin_amdgcn_s_barrier();  /* CUR free for next iter's DMA */       \
    }

    for (int g = 0; g < NT / 2; ++g) {
        ITER(2 * g,     0, 1)
        ITER(2 * g + 1, 1, 0)
    }
#undef ITER
#undef STAGE_AB

    // epilogue: D layout col = lane&15, row = (lane>>4)*4 + j  [m89-verified]
    #pragma unroll
    for (int n = 0; n < NF; ++n) {
        int col = wc * (BN / 2) + n * 16 + lr;
        float bv = bias[col];
        #pragma unroll
        for (int j = 0; j < 4; ++j) {
            int row = row0 + wr * 16 + lk * 4 + j;
            float v = acc[n][j] + bv;
            if (RELU) v = fmaxf(v, 0.f);
            out[(size_t)row * BN + col] = v;
        }
    }
}

extern "C" void kernel_launch(void* const* d_in, const int* in_sizes, int n_in,
                              void* d_out, int out_size, void* d_ws, size_t ws_size,
                              hipStream_t stream) {
    const int N = 16384, NH1 = 128, NH2 = 64;
    const float* feature = (const float*)d_in[0];
    const float* adj     = (const float*)d_in[1];
    const float* W1      = (const float*)d_in[2];
    const float* b1      = (const float*)d_in[3];
    const float* W2      = (const float*)d_in[4];
    const float* b2      = (const float*)d_in[5];

    short* S1t = (short*)d_ws;                            // [128][16384] bf16, 4 MiB
    float* h   = (float*)((char*)d_ws + (4u << 20));      // [16384][128] fp32, 8 MiB
    short* S2t = (short*)((char*)d_ws + (12u << 20));     // [64][16384]  bf16, 2 MiB

    k_xw_t<NH1><<<N / 64, 256, 0, stream>>>(feature, W1, S1t, N);
    k_adj_gemm<NH1, true ><<<N / 32, 256, 0, stream>>>(adj, S1t, b1, h, N, N);
    k_xw_t<NH2><<<N / 64, 256, 0, stream>>>(h, W2, S2t, N);
    k_adj_gemm<NH2, false><<<N / 32, 256, 0, stream>>>(adj, S2t, b2, (float*)d_out, N, N);
    (void)in_sizes; (void)n_in; (void)out_size; (void)ws_size;
}

// Round 8
// 533.887 us; speedup vs baseline: 1.5266x; 1.0824x over previous
//
#include <hip/hip_runtime.h>
#include <stdint.h>

typedef float  f32x4  __attribute__((ext_vector_type(4)));
typedef short  short8 __attribute__((ext_vector_type(8)));
typedef __bf16 bf16x8 __attribute__((ext_vector_type(8)));

__device__ __forceinline__ unsigned short f2bf(float f) {
    unsigned u = __builtin_bit_cast(unsigned, f);
    unsigned r = u + 0x7fffu + ((u >> 16) & 1u);   // round-to-nearest-even
    return (unsigned short)(r >> 16);
}

__device__ __forceinline__ short8 cvt8(f32x4 a, f32x4 b) {
    short8 r;
    r[0] = (short)f2bf(a[0]); r[1] = (short)f2bf(a[1]);
    r[2] = (short)f2bf(a[2]); r[3] = (short)f2bf(a[3]);
    r[4] = (short)f2bf(b[0]); r[5] = (short)f2bf(b[1]);
    r[6] = (short)f2bf(b[2]); r[7] = (short)f2bf(b[3]);
    return r;
}

typedef const __attribute__((address_space(1))) void* gas_p;
typedef __attribute__((address_space(3))) void*       las_p;
__device__ __forceinline__ void gld_lds16(const void* g, void* l) {
    __builtin_amdgcn_global_load_lds((gas_p)g, (las_p)l, 16, 0, 0);
}

__device__ __forceinline__ f32x4 mfma16(short8 a, short8 b, f32x4 c) {
    return __builtin_amdgcn_mfma_f32_16x16x32_bf16(
        __builtin_bit_cast(bf16x8, a), __builtin_bit_cast(bf16x8, b), c, 0, 0, 0);
}

// ---------------------------------------------------------------------------
// Small GEMM:  St[n][m] = sum_k X[m][k] * W[k][n]   (K = 128 fixed)
// (unchanged — validated, ~2% of runtime)
// ---------------------------------------------------------------------------
template<int NMAT>
__global__ __launch_bounds__(256) void k_xw_t(const float* __restrict__ X,
                                              const float* __restrict__ W,
                                              short* __restrict__ St, int M) {
    constexpr int K   = 128;
    constexpr int NPT = NMAT / 4;
    __shared__ float Xs[64][129];
    __shared__ float Ws[K][NMAT];

    const int tid = threadIdx.x;
    const int m0  = blockIdx.x * 64;

    constexpr int WCH = K * NMAT / 4 / 256;
    #pragma unroll
    for (int j = 0; j < WCH; ++j) {
        int ch = tid + j * 256;
        ((float4*)Ws)[ch] = ((const float4*)W)[ch];
    }
    #pragma unroll
    for (int j = 0; j < 8; ++j) {
        int ch = tid + j * 256;
        int r = ch >> 5, c4 = ch & 31;
        float4 v = *(const float4*)(X + (size_t)(m0 + r) * K + c4 * 4);
        Xs[r][c4 * 4 + 0] = v.x; Xs[r][c4 * 4 + 1] = v.y;
        Xs[r][c4 * 4 + 2] = v.z; Xs[r][c4 * 4 + 3] = v.w;
    }
    __syncthreads();

    const int m  = tid & 63;
    const int n0 = (tid >> 6) * NPT;
    float acc[NPT];
    #pragma unroll
    for (int i = 0; i < NPT; ++i) acc[i] = 0.f;

    for (int k = 0; k < K; ++k) {
        float x = Xs[m][k];
        #pragma unroll
        for (int i = 0; i < NPT; i += 4) {
            float4 w = *(const float4*)&Ws[k][n0 + i];
            acc[i + 0] += x * w.x; acc[i + 1] += x * w.y;
            acc[i + 2] += x * w.z; acc[i + 3] += x * w.w;
        }
    }
    #pragma unroll
    for (int i = 0; i < NPT; ++i)
        St[(size_t)(n0 + i) * M + m0 + m] = (short)f2bf(acc[i]);
}

// ---------------------------------------------------------------------------
// Streaming GEMM:  out[m][n] = sum_k adj[m][k] * S[k][n]  (+bias, opt. relu)
//  v8 = v7 with the As allocation fixed (was [4][BM*16] = 2 KB/buf while DMA
//  writes 8 KB/tile -> buffers aliased -> r7 correctness failure).
//  - BM=32, 256 threads / 4 waves (2M x 2N), grid 512 -> 2 blocks/CU,
//    8 waves/CU = 2 waves/SIMD. Zero duplicated global reads (r5 lesson).
//  - A (HBM, ~900cyc): QUAD-buffered (4 x 8 KB), staged 2 iters ahead.
//    B (L2-resident S^T, ~200cyc): double-buffered, 1 iter ahead.
//  - Issue order per iter: B(t+1) then A(t+2); per-wave vmcnt(BCH+2*ACH)
//    guarantees exactly {A(t),B(t)} landed; A(t+1),B(t+1),A(t+2) stay in
//    flight across barriers. Prologue A(0),B(0),A(1) is steady-state-
//    identical for iter 0's accounting.
//  - Both-sides XOR swizzle (row&7)<<4, linear LDS dest, pre-swizzled source
//    -> conflict-free ds_read_b128 on A and B.
// ---------------------------------------------------------------------------
template<int BN, bool RELU>
__global__ __launch_bounds__(256, 2) void k_adj_gemm(const float* __restrict__ A,
                                                     const short* __restrict__ Bt,
                                                     const float* __restrict__ bias,
                                                     float* __restrict__ out,
                                                     int M, int K) {
    constexpr int BM    = 32, BK = 64;
    constexpr int NF    = BN / 32;                    // n-frags per wave (4 or 2)
    constexpr int ACH   = BM * BK * 4 / (256 * 16);   // 2 A-DMA per thread
    constexpr int BCH   = BN * BK * 2 / (256 * 16);   // 4 or 2 B-DMA per thread
    constexpr int VMCNT = BCH + 2 * ACH;              // newer than {A(t),B(t)}

    __shared__ float As[4][BM * 64];                  // 4 x 8 KB  (r7 fix)
    __shared__ short Bs[2][BN * 64];                  // 2 x 16/8 KB

    const int tid  = threadIdx.x;
    const int wave = tid >> 6, lane = tid & 63;
    const int lr   = lane & 15, lk = lane >> 4;
    const int wr   = wave >> 1, wc = wave & 1;
    const int row0 = blockIdx.x * BM;
    const int cbB  = wc * (BN / 2) * 128;             // wave's B col-base (bytes)
    const int key  = (lr & 7) << 4;                   // XOR swizzle key

    // per-lane LDS read offsets
    const int aRow   = (wr * 16 + lr) * 256;          // A row base (bytes)
    const int aO0    = (lk * 32) ^ key,       aO0b = (lk * 32 + 16) ^ key;
    const int aO1    = (128 + lk * 32) ^ key, aO1b = (128 + lk * 32 + 16) ^ key;
    const int offs0  = (lk * 16) ^ key;               // B k-half 0
    const int offs1  = (64 + lk * 16) ^ key;          // B k-half 1

    f32x4 acc[NF];
    #pragma unroll
    for (int n = 0; n < NF; ++n) acc[n] = (f32x4)0.f;

    const int NT = K / BK;                            // 256

#define STAGE_A(BUF, KT)                                                        \
    {                                                                           \
        _Pragma("unroll")                                                       \
        for (int j = 0; j < ACH; ++j) {                                         \
            int o = (tid + j * 256) * 16;        /* linear byte off, A tile */  \
            int r = o >> 8, w = o & 255;                                        \
            const char* src = (const char*)A + (size_t)(row0 + r) * K * 4       \
                              + (size_t)(KT) * 256 + (w ^ ((r & 7) << 4));      \
            gld_lds16(src, (char*)&As[BUF][0] + o);                             \
        }                                                                       \
    }
#define STAGE_B(BUF, KT)                                                        \
    {                                                                           \
        _Pragma("unroll")                                                       \
        for (int j = 0; j < BCH; ++j) {                                         \
            int o = (tid + j * 256) * 16;        /* linear byte off, B tile */  \
            int r = o >> 7, w = o & 127;                                        \
            const char* src = (const char*)Bt + (size_t)r * (K * 2)             \
                              + (size_t)(KT) * 128 + (w ^ ((r & 7) << 4));      \
            gld_lds16(src, (char*)&Bs[BUF][0] + o);                             \
        }                                                                       \
    }

    // prologue (issue order matters for vmcnt accounting)
    STAGE_A(0, 0)
    STAGE_B(0, 0)
    STAGE_A(1, 1)

#define ITER(KT, CA, NA, CB, NB)                                                \
    {                                                                           \
        /* P1: B one ahead, A two ahead (clamped tails keep counts uniform) */  \
        { int ktn = (KT) + 1 < NT ? (KT) + 1 : NT - 1; STAGE_B(NB, ktn) }       \
        { int kta = (KT) + 2 < NT ? (KT) + 2 : NT - 1; STAGE_A(NA, kta) }       \
        __builtin_amdgcn_sched_barrier(0);                                      \
        /* P2: {A(t),B(t)} landed; newer DMA stays in flight */                 \
        asm volatile("s_waitcnt vmcnt(%0)" :: "i"(VMCNT) : "memory");           \
        __builtin_amdgcn_s_barrier();                                           \
        __builtin_amdgcn_sched_barrier(0);                                      \
        /* P3: A frags from LDS, cvt fp32->bf16 */                              \
        const char* Ab = (const char*)&As[CA][0] + aRow;                        \
        f32x4 A0a = *(const f32x4*)(Ab + aO0);                                  \
        f32x4 A0b = *(const f32x4*)(Ab + aO0b);                                 \
        f32x4 A1a = *(const f32x4*)(Ab + aO1);                                  \
        f32x4 A1b = *(const f32x4*)(Ab + aO1b);                                 \
        short8 fa0 = cvt8(A0a, A0b);                                            \
        short8 fa1 = cvt8(A1a, A1b);                                            \
        /* P4: MFMA over this wave's n-frags, both K-halves */                  \
        _Pragma("unroll")                                                       \
        for (int n = 0; n < NF; ++n) {                                          \
            short8 b0 = *(const short8*)((const char*)&Bs[CB][0]                \
                                         + cbB + n * 2048 + lr * 128 + offs0);  \
            acc[n] = mfma16(fa0, b0, acc[n]);                                   \
            short8 b1 = *(const short8*)((const char*)&Bs[CB][0]                \
                                         + cbB + n * 2048 + lr * 128 + offs1);  \
            acc[n] = mfma16(fa1, b1, acc[n]);                                   \
        }                                                                       \
        __builtin_amdgcn_sched_barrier(0);                                      \
        __builtin_amdgcn_s_barrier();  /* CB/CA free for future staging */      \
    }

    for (int g = 0; g < NT / 4; ++g) {
        ITER(4 * g + 0, 0, 2, 0, 1)
        ITER(4 * g + 1, 1, 3, 1, 0)
        ITER(4 * g + 2, 2, 0, 0, 1)
        ITER(4 * g + 3, 3, 1, 1, 0)
    }
#undef ITER
#undef STAGE_A
#undef STAGE_B

    // epilogue: D layout col = lane&15, row = (lane>>4)*4 + j  [m89-verified]
    #pragma unroll
    for (int n = 0; n < NF; ++n) {
        int col = wc * (BN / 2) + n * 16 + lr;
        float bv = bias[col];
        #pragma unroll
        for (int j = 0; j < 4; ++j) {
            int row = row0 + wr * 16 + lk * 4 + j;
            float v = acc[n][j] + bv;
            if (RELU) v = fmaxf(v, 0.f);
            out[(size_t)row * BN + col] = v;
        }
    }
}

extern "C" void kernel_launch(void* const* d_in, const int* in_sizes, int n_in,
                              void* d_out, int out_size, void* d_ws, size_t ws_size,
                              hipStream_t stream) {
    const int N = 16384, NH1 = 128, NH2 = 64;
    const float* feature = (const float*)d_in[0];
    const float* adj     = (const float*)d_in[1];
    const float* W1      = (const float*)d_in[2];
    const float* b1      = (const float*)d_in[3];
    const float* W2      = (const float*)d_in[4];
    const float* b2      = (const float*)d_in[5];

    short* S1t = (short*)d_ws;                            // [128][16384] bf16, 4 MiB
    float* h   = (float*)((char*)d_ws + (4u << 20));      // [16384][128] fp32, 8 MiB
    short* S2t = (short*)((char*)d_ws + (12u << 20));     // [64][16384]  bf16, 2 MiB

    k_xw_t<NH1><<<N / 64, 256, 0, stream>>>(feature, W1, S1t, N);
    k_adj_gemm<NH1, true ><<<N / 32, 256, 0, stream>>>(adj, S1t, b1, h, N, N);
    k_xw_t<NH2><<<N / 64, 256, 0, stream>>>(h, W2, S2t, N);
    k_adj_gemm<NH2, false><<<N / 32, 256, 0, stream>>>(adj, S2t, b2, (float*)d_out, N, N);
    (void)in_sizes; (void)n_in; (void)out_size; (void)ws_size;
}

// Round 9
// 533.537 us; speedup vs baseline: 1.5276x; 1.0007x over previous
//
#include <hip/hip_runtime.h>
#include <stdint.h>

typedef float  f32x4  __attribute__((ext_vector_type(4)));
typedef short  short8 __attribute__((ext_vector_type(8)));
typedef __bf16 bf16x8 __attribute__((ext_vector_type(8)));

__device__ __forceinline__ unsigned short f2bf(float f) {
    unsigned u = __builtin_bit_cast(unsigned, f);
    unsigned r = u + 0x7fffu + ((u >> 16) & 1u);   // round-to-nearest-even
    return (unsigned short)(r >> 16);
}

__device__ __forceinline__ short8 cvt8(f32x4 a, f32x4 b) {
    short8 r;
    r[0] = (short)f2bf(a[0]); r[1] = (short)f2bf(a[1]);
    r[2] = (short)f2bf(a[2]); r[3] = (short)f2bf(a[3]);
    r[4] = (short)f2bf(b[0]); r[5] = (short)f2bf(b[1]);
    r[6] = (short)f2bf(b[2]); r[7] = (short)f2bf(b[3]);
    return r;
}

typedef const __attribute__((address_space(1))) void* gas_p;
typedef __attribute__((address_space(3))) void*       las_p;
__device__ __forceinline__ void gld_lds16(const void* g, void* l) {
    __builtin_amdgcn_global_load_lds((gas_p)g, (las_p)l, 16, 0, 0);
}

__device__ __forceinline__ f32x4 mfma16(short8 a, short8 b, f32x4 c) {
    return __builtin_amdgcn_mfma_f32_16x16x32_bf16(
        __builtin_bit_cast(bf16x8, a), __builtin_bit_cast(bf16x8, b), c, 0, 0, 0);
}

// ---------------------------------------------------------------------------
// Small GEMM:  St[n][m] = sum_k X[m][k] * W[k][n]   (K = 128 fixed)
// (unchanged — validated, ~2% of runtime)
// ---------------------------------------------------------------------------
template<int NMAT>
__global__ __launch_bounds__(256) void k_xw_t(const float* __restrict__ X,
                                              const float* __restrict__ W,
                                              short* __restrict__ St, int M) {
    constexpr int K   = 128;
    constexpr int NPT = NMAT / 4;
    __shared__ float Xs[64][129];
    __shared__ float Ws[K][NMAT];

    const int tid = threadIdx.x;
    const int m0  = blockIdx.x * 64;

    constexpr int WCH = K * NMAT / 4 / 256;
    #pragma unroll
    for (int j = 0; j < WCH; ++j) {
        int ch = tid + j * 256;
        ((float4*)Ws)[ch] = ((const float4*)W)[ch];
    }
    #pragma unroll
    for (int j = 0; j < 8; ++j) {
        int ch = tid + j * 256;
        int r = ch >> 5, c4 = ch & 31;
        float4 v = *(const float4*)(X + (size_t)(m0 + r) * K + c4 * 4);
        Xs[r][c4 * 4 + 0] = v.x; Xs[r][c4 * 4 + 1] = v.y;
        Xs[r][c4 * 4 + 2] = v.z; Xs[r][c4 * 4 + 3] = v.w;
    }
    __syncthreads();

    const int m  = tid & 63;
    const int n0 = (tid >> 6) * NPT;
    float acc[NPT];
    #pragma unroll
    for (int i = 0; i < NPT; ++i) acc[i] = 0.f;

    for (int k = 0; k < K; ++k) {
        float x = Xs[m][k];
        #pragma unroll
        for (int i = 0; i < NPT; i += 4) {
            float4 w = *(const float4*)&Ws[k][n0 + i];
            acc[i + 0] += x * w.x; acc[i + 1] += x * w.y;
            acc[i + 2] += x * w.z; acc[i + 3] += x * w.w;
        }
    }
    #pragma unroll
    for (int i = 0; i < NPT; ++i)
        St[(size_t)(n0 + i) * M + m0 + m] = (short)f2bf(acc[i]);
}

// ---------------------------------------------------------------------------
// Streaming GEMM:  out[m][n] = sum_k adj[m][k] * S[k][n]  (+bias, opt. relu)
//  v9: cut per-iteration overhead (r8 post-mortem: r4==r8 at ~535 despite
//  occupancy/depth changes -> residual is per-iter cost: 2 barriers + A's
//  fp32 double-pass through LDS + B read-amplification).
//  - BM=64, 256 thr, 4 waves = 4M x 1N: each wave OWNS 16 rows exclusively.
//    A: global->reg dwordx4 (frag-exact r4 addressing), cvt in reg, 2 tiles
//    deep. A never in LDS, zero duplicated loads (r5 lesson).
//  - B: global_load_lds DMA, TRIPLE-buffered -> stage target's last readers
//    finished before the PREVIOUS barrier => ONE barrier per iter is safe.
//  - Per-iter order: cvt A(t) | refill A(t+2) | stage B(t+1) | vmcnt(BCH+4)
//    | s_barrier | MFMA. vmcnt keeps {A(t+2),B(t+1)} in flight, forces
//    {B(t),A(t+1)} (issued >=1 iter ago) retired. Prologue A(0),A(1),B(0)
//    is steady-state-identical. Rotation period 6 (A%2, B%3), NT=256=42*6+4.
//  - XOR swizzle (row&7)<<4 on B (pre-swizzled DMA source, linear dest).
// ---------------------------------------------------------------------------
template<int BN, bool RELU>
__global__ __launch_bounds__(256, 2) void k_adj_gemm(const float* __restrict__ A,
                                                     const short* __restrict__ Bt,
                                                     const float* __restrict__ bias,
                                                     float* __restrict__ out,
                                                     int M, int K) {
    constexpr int BM    = 64, BK = 64;
    constexpr int NF    = BN / 16;                    // n-frags (full width): 8 or 4
    constexpr int BCH   = BN * BK * 2 / (256 * 16);   // B-DMA per thread: 4 or 2
    constexpr int VMCNT = BCH + 4;                    // keep {B(t+1), A(t+2)}

    __shared__ short Bs[3][BN * 64];                  // 3 x 16/8 KB

    const int tid  = threadIdx.x;
    const int wave = tid >> 6, lane = tid & 63;
    const int lr   = lane & 15, lk = lane >> 4;
    const int row0 = blockIdx.x * BM;
    const int row_g = row0 + wave * 16 + lr;          // wave-exclusive rows

    const char* Abase = (const char*)A + (size_t)row_g * K * 4 + lk * 32;

    const int key   = (lr & 7) << 4;                  // XOR swizzle key
    const int offs0 = (lk * 16) ^ key;                // B k-half 0
    const int offs1 = (64 + lk * 16) ^ key;           // B k-half 1

    f32x4 acc[NF];
    #pragma unroll
    for (int n = 0; n < NF; ++n) acc[n] = (f32x4)0.f;

    f32x4 a0[4], a1[4];                               // A slots, 2 tiles deep
    const int NT = K / BK;                            // 256

#define LOAD_A(SLOT, KT)                                                        \
    {                                                                           \
        const char* p = Abase + (size_t)(KT) * 256;                             \
        SLOT[0] = *(const f32x4*)(p);                                           \
        SLOT[1] = *(const f32x4*)(p + 16);                                      \
        SLOT[2] = *(const f32x4*)(p + 128);                                     \
        SLOT[3] = *(const f32x4*)(p + 144);                                     \
    }
#define STAGE_B(BUF, KT)                                                        \
    {                                                                           \
        _Pragma("unroll")                                                       \
        for (int j = 0; j < BCH; ++j) {                                         \
            int o = (tid + j * 256) * 16;        /* linear byte off, B tile */  \
            int r = o >> 7, w = o & 127;                                        \
            const char* src = (const char*)Bt + (size_t)r * (K * 2)             \
                              + (size_t)(KT) * 128 + (w ^ ((r & 7) << 4));      \
            gld_lds16(src, (char*)&Bs[BUF][0] + o);                             \
        }                                                                       \
    }

    // prologue (issue order matches steady state: A..., B last-but-4)
    LOAD_A(a0, 0)
    LOAD_A(a1, 1)
    STAGE_B(0, 0)

#define ITER(KT, SA, CB, NB)                                                    \
    {                                                                           \
        /* cvt A(t) -> bf16 frags (compiler auto-waits exactly on SA regs) */   \
        short8 fa0 = cvt8(SA[0], SA[1]);                                        \
        short8 fa1 = cvt8(SA[2], SA[3]);                                        \
        /* refill slot with A(t+2), stage B(t+1) (clamped tails, uniform) */    \
        { int kta = (KT) + 2 < NT ? (KT) + 2 : NT - 1; LOAD_A(SA, kta) }        \
        { int ktn = (KT) + 1 < NT ? (KT) + 1 : NT - 1; STAGE_B(NB, ktn) }       \
        __builtin_amdgcn_sched_barrier(0);                                      \
        /* {B(t),A(t+1)} retired; {B(t+1),A(t+2)} stay in flight */             \
        asm volatile("s_waitcnt vmcnt(%0)" :: "i"(VMCNT) : "memory");           \
        __builtin_amdgcn_s_barrier();            /* the ONLY barrier */         \
        __builtin_amdgcn_sched_barrier(0);                                      \
        /* MFMA over full width, both K-halves */                               \
        _Pragma("unroll")                                                       \
        for (int n = 0; n < NF; ++n) {                                          \
            short8 b0 = *(const short8*)((const char*)&Bs[CB][0]                \
                                         + n * 2048 + lr * 128 + offs0);        \
            acc[n] = mfma16(fa0, b0, acc[n]);                                   \
            short8 b1 = *(const short8*)((const char*)&Bs[CB][0]                \
                                         + n * 2048 + lr * 128 + offs1);        \
            acc[n] = mfma16(fa1, b1, acc[n]);                                   \
        }                                                                       \
    }

    // period-6 rotation (A slot %2, B buf %3): 42*6 = 252 iters + 4 tail
    for (int g = 0; g < 42; ++g) {
        int t = g * 6;
        ITER(t + 0, a0, 0, 1)
        ITER(t + 1, a1, 1, 2)
        ITER(t + 2, a0, 2, 0)
        ITER(t + 3, a1, 0, 1)
        ITER(t + 4, a0, 1, 2)
        ITER(t + 5, a1, 2, 0)
    }
    ITER(252, a0, 0, 1)
    ITER(253, a1, 1, 2)
    ITER(254, a0, 2, 0)
    ITER(255, a1, 0, 1)
#undef ITER
#undef LOAD_A
#undef STAGE_B

    // epilogue: D layout col = lane&15, row = (lane>>4)*4 + j  [m89-verified]
    #pragma unroll
    for (int n = 0; n < NF; ++n) {
        int col = n * 16 + lr;
        float bv = bias[col];
        #pragma unroll
        for (int j = 0; j < 4; ++j) {
            int row = row0 + wave * 16 + lk * 4 + j;
            float v = acc[n][j] + bv;
            if (RELU) v = fmaxf(v, 0.f);
            out[(size_t)row * BN + col] = v;
        }
    }
}

extern "C" void kernel_launch(void* const* d_in, const int* in_sizes, int n_in,
                              void* d_out, int out_size, void* d_ws, size_t ws_size,
                              hipStream_t stream) {
    const int N = 16384, NH1 = 128, NH2 = 64;
    const float* feature = (const float*)d_in[0];
    const float* adj     = (const float*)d_in[1];
    const float* W1      = (const float*)d_in[2];
    const float* b1      = (const float*)d_in[3];
    const float* W2      = (const float*)d_in[4];
    const float* b2      = (const float*)d_in[5];

    short* S1t = (short*)d_ws;                            // [128][16384] bf16, 4 MiB
    float* h   = (float*)((char*)d_ws + (4u << 20));      // [16384][128] fp32, 8 MiB
    short* S2t = (short*)((char*)d_ws + (12u << 20));     // [64][16384]  bf16, 2 MiB

    k_xw_t<NH1><<<N / 64, 256, 0, stream>>>(feature, W1, S1t, N);
    k_adj_gemm<NH1, true ><<<N / 64, 256, 0, stream>>>(adj, S1t, b1, h, N, N);
    k_xw_t<NH2><<<N / 64, 256, 0, stream>>>(h, W2, S2t, N);
    k_adj_gemm<NH2, false><<<N / 64, 256, 0, stream>>>(adj, S2t, b2, (float*)d_out, N, N);
    (void)in_sizes; (void)n_in; (void)out_size; (void)ws_size;
}